// Round 1
// baseline (1838.462 us; speedup 1.0000x reference)
//
#include <hip/hip_runtime.h>
#include <stdint.h>

#define NM 128   // matrix dim / electrons
#define NT 128   // threads per block (2 waves)

// Physical float4 slot for logical (row i, float4-col j4).
// Per-row rotation by i makes BOTH row-direction (lanes over j4) and
// column-lockstep (lanes over i, same j4) accesses conflict-free on the
// 32 LDS banks, with zero padding (stays exactly 64KB for the matrix).
__device__ __forceinline__ int slot4(int i, int j4) {
    return (i << 5) + ((j4 + i) & 31);
}
// float index of scalar element (i, j)
__device__ __forceinline__ int fidx(int i, int j) {
    return (slot4(i, j >> 2) << 2) + (j & 3);
}

__global__ __launch_bounds__(NT, 1)
void slater_logdet(const float* __restrict__ rs,
                   const float* __restrict__ kpts,
                   const float* __restrict__ csw,
                   const float* __restrict__ ssw,
                   float* __restrict__ out) {
    // 65536 B matrix + 24 B scratch: relies on gfx950 160 KiB workgroup LDS.
    __shared__ __align__(16) float S[NM * NM];
    __shared__ unsigned long long red[2];
    __shared__ float redf[2];

    const int t   = threadIdx.x;
    const int b   = blockIdx.x;
    const int wid = t >> 6;

    // Own particle position (coalesced-ish 12B/lane)
    const float x = rs[(b * NM + t) * 3 + 0];
    const float y = rs[(b * NM + t) * 3 + 1];
    const float z = rs[(b * NM + t) * 3 + 2];

    const int trot     = t & 31;
    const int trowbase = t << 7;  // t * 128 floats

    // ---- Fill: row t of Slater matrix.  S[t][m] = cs[m]*cos(k_m.r) - ss[m]*sin(k_m.r)
    // kpts/csw/ssw indices are wave-uniform -> compiler emits scalar loads (L1-hot).
    for (int m4 = 0; m4 < 32; ++m4) {
        float4 v;
#pragma unroll
        for (int e = 0; e < 4; ++e) {
            const int m = m4 * 4 + e;
            const float d = kpts[m * 3 + 0] * x + kpts[m * 3 + 1] * y + kpts[m * 3 + 2] * z;
            float sn, cn;
            __sincosf(d, &sn, &cn);
            const float val = csw[m] * cn - ssw[m] * sn;
            if (e == 0) v.x = val;
            else if (e == 1) v.y = val;
            else if (e == 2) v.z = val;
            else v.w = val;
        }
        *(float4*)&S[trowbase + (((m4 + t) & 31) << 2)] = v;
    }
    __syncthreads();

    // ---- LU with partial pivoting; only U's diagonal is needed.
    for (int k = 0; k < NM - 1; ++k) {
        // pivot scan: thread t reads S(t,k)  (8-way conflicted column read)
        float sval = S[fidx(t, k)];
        unsigned long long pk = (t >= k)
            ? ((((unsigned long long)__float_as_uint(fabsf(sval))) << 32) | (unsigned)t)
            : 0ull;
#pragma unroll
        for (int off = 32; off > 0; off >>= 1) {
            unsigned long long o = __shfl_xor(pk, off, 64);
            pk = (o > pk) ? o : pk;
        }
        if ((t & 63) == 0) red[wid] = pk;
        __syncthreads();
        const unsigned long long m0 = red[0], m1 = red[1];
        const unsigned long long mm = (m1 > m0) ? m1 : m0;
        const int p = (int)(unsigned)(mm & 0xffffffffull);

        const float piv = S[fidx(p, k)];  // broadcast read (conflict-free)

        if (p != k) {                 // uniform branch
            __syncthreads();          // everyone has read piv before rows move
            if (t < 32) {             // swap full rows k<->p, one float4 col per lane
                const int sa = (slot4(k, t)) << 2;
                const int sb = (slot4(p, t)) << 2;
                const float4 a = *(float4*)&S[sa];
                const float4 c = *(float4*)&S[sb];
                *(float4*)&S[sa] = c;
                *(float4*)&S[sb] = a;
            }
            __syncthreads();
            if (t == p) sval = S[fidx(t, k)];  // row p now holds old row k value
        }

        // scale + rank-1 update; L is never stored (cols < k are dead).
        if (t > k) {
            const float l = sval / piv;
            const int kq    = k >> 2;
            const int kbase = k << 7;
            const int krot  = k & 31;
            for (int j4 = kq; j4 < 32; ++j4) {
                const float4 u = *(float4*)&S[kbase + (((j4 + krot) & 31) << 2)];   // broadcast
                float4 v = *(float4*)&S[trowbase + (((j4 + trot) & 31) << 2)];
                v.x -= l * u.x; v.y -= l * u.y; v.z -= l * u.z; v.w -= l * u.w;
                *(float4*)&S[trowbase + (((j4 + trot) & 31) << 2)] = v;
            }
        }
        __syncthreads();
    }

    // ---- log|det| = sum log|U_kk|
    float lg = __logf(fabsf(S[fidx(t, t)]));
#pragma unroll
    for (int off = 32; off > 0; off >>= 1)
        lg += __shfl_xor(lg, off, 64);
    if ((t & 63) == 0) redf[wid] = lg;
    __syncthreads();
    if (t == 0) out[b] = redf[0] + redf[1];
}

extern "C" void kernel_launch(void* const* d_in, const int* in_sizes, int n_in,
                              void* d_out, int out_size, void* d_ws, size_t ws_size,
                              hipStream_t stream) {
    const float* rs = (const float*)d_in[0];
    const float* kp = (const float*)d_in[1];
    const float* cs = (const float*)d_in[2];
    const float* ss = (const float*)d_in[3];
    float* out = (float*)d_out;
    const int batch = in_sizes[0] / (NM * 3);  // 4096
    slater_logdet<<<dim3(batch), dim3(NT), 0, stream>>>(rs, kp, cs, ss, out);
}

// Round 2
// 1055.167 us; speedup vs baseline: 1.7423x; 1.7423x over previous
//
#include <hip/hip_runtime.h>
#include <stdint.h>

#define NM 128   // matrix dim / electrons
#define NT 512   // 8 waves; thread t: h = t>>7 (column chunk), r = t&127 (row)

// Each thread owns a 32-column register chunk of one row:
//   thread (r, h) holds S[r][32h .. 32h+31] in float s[32].
// LU with virtual partial pivoting (no row swaps; 'elim' flags).
// Per step k:
//   group hk (=k>>5, 2 waves) reduces argmax_{r not elim} |S[r][k]| with a
//   32-bit quantized key; pivot row p publishes its chunks to LDS prow[];
//   group hk publishes raw column values colv[]; everyone updates registers
//   against broadcast prow reads. Matrix never round-trips through LDS.
__global__ __launch_bounds__(NT, 4)
void slater_logdet(const float* __restrict__ rs,
                   const float* __restrict__ kpts,
                   const float* __restrict__ csw,
                   const float* __restrict__ ssw,
                   float* __restrict__ out) {
    __shared__ __align__(16) float prow[NM];  // published pivot row
    __shared__ float colv[NM];                // published column-k values
    __shared__ unsigned int red[2];           // per-wave argmax keys (group hk)

    const int t  = threadIdx.x;
    const int b  = blockIdx.x;
    const int h  = t >> 7;
    const int r  = t & 127;
    const int c0 = h << 5;

    // particle r position
    const float x = rs[(b * NM + r) * 3 + 0];
    const float y = rs[(b * NM + r) * 3 + 1];
    const float z = rs[(b * NM + r) * 3 + 2];

    // fill: s[j] = cs[m]*cos(k_m.r) - ss[m]*sin(k_m.r),  m = c0 + j
    float s[32];
#pragma unroll
    for (int j = 0; j < 32; ++j) {
        const int m = c0 + j;
        const float d = kpts[m * 3 + 0] * x + kpts[m * 3 + 1] * y + kpts[m * 3 + 2] * z;
        float sn, cn;
        __sincosf(d, &sn, &cn);
        s[j] = csw[m] * cn - ssw[m] * sn;
    }

    bool  elim = false;
    float sval = s[0];   // column-k candidate; valid for group h==0 at k=0
    float acc  = 0.0f;   // log|det| accumulator (thread 0)

    for (int k = 0; k < NM; ++k) {
        // ---- phase 1: argmax over column k (group hk only) ----
        if (h == (k >> 5)) {
            unsigned key = elim ? 0u
                : ((((__float_as_uint(sval) & 0x7fffffffu) >> 6) << 7) | (unsigned)r);
#pragma unroll
            for (int off = 32; off > 0; off >>= 1) {
                const unsigned o = __shfl_xor(key, off, 64);
                key = o > key ? o : key;
            }
            if ((t & 63) == 0) red[(t >> 6) & 1] = key;
        }
        __syncthreads();  // #1
        const unsigned k0 = red[0], k1 = red[1];
        const int p = (int)((k0 > k1 ? k0 : k1) & 127u);

        // ---- phase 2: publish pivot row + column values ----
        if (h == (k >> 5)) colv[r] = (elim || r == p) ? 0.0f : sval;
        if (r == p) {
            if (c0 + 31 >= k) {  // only live chunks are ever read
                float4* pr4 = (float4*)&prow[c0];
#pragma unroll
                for (int j4 = 0; j4 < 8; ++j4)
                    pr4[j4] = make_float4(s[4 * j4 + 0], s[4 * j4 + 1],
                                          s[4 * j4 + 2], s[4 * j4 + 3]);
            }
            elim = true;
        }
        __syncthreads();  // #2

        const float piv = prow[k];  // exact pivot (broadcast read)
        if (t == 0) acc += __logf(fabsf(piv));

        // ---- phase 3: rank-1 update in registers (live chunks only) ----
        if (k < NM - 1 && c0 + 31 >= k) {
            const float l = colv[r] / piv;   // 0 for eliminated rows
            const float4* pr4 = (const float4*)&prow[c0];
#pragma unroll
            for (int j4 = 0; j4 < 8; ++j4) {
                const float4 u = pr4[j4];
                s[4 * j4 + 0] -= l * u.x;
                s[4 * j4 + 1] -= l * u.y;
                s[4 * j4 + 2] -= l * u.z;
                s[4 * j4 + 3] -= l * u.w;
            }
            // capture next pivot-column candidate (owning group only);
            // constant-index select chain keeps s[] in registers.
            if (h == ((k + 1) >> 5)) {
                const int jt = (k + 1) & 31;
                float nv = s[0];
#pragma unroll
                for (int j = 1; j < 32; ++j) nv = (jt == j) ? s[j] : nv;
                sval = nv;
            }
        }
        // no barrier needed here: next step's LDS writes are fenced by sync #1
    }

    if (t == 0) out[b] = acc;
}

extern "C" void kernel_launch(void* const* d_in, const int* in_sizes, int n_in,
                              void* d_out, int out_size, void* d_ws, size_t ws_size,
                              hipStream_t stream) {
    const float* rs = (const float*)d_in[0];
    const float* kp = (const float*)d_in[1];
    const float* cs = (const float*)d_in[2];
    const float* ss = (const float*)d_in[3];
    float* out = (float*)d_out;
    const int batch = in_sizes[0] / (NM * 3);  // 4096
    slater_logdet<<<dim3(batch), dim3(NT), 0, stream>>>(rs, kp, cs, ss, out);
}